// Round 12
// baseline (458.107 us; speedup 1.0000x reference)
//
#include <hip/hip_runtime.h>
#include <math.h>

#define HW 16384
#define B_ 8
#define C_ 256
#define S_ 64
#define K_ 8

typedef __attribute__((ext_vector_type(8))) short bf16x8;
typedef __attribute__((ext_vector_type(4))) float f32x4;

__device__ __forceinline__ float sigmoidf_(float z) { return 1.f / (1.f + __expf(-z)); }

__device__ __forceinline__ unsigned bf16rne_(float f) {
    unsigned u = __float_as_uint(f);
    return (u + 0x7fffu + ((u >> 16) & 1u)) >> 16;
}

// ---------------- K0: Wtb = bf16(wproj^T) PRE-SWIZZLED [s][c] (idx ^ ((s&7)<<3));
//                  iva2[c][0..7]=aiv[k], [8..15]=iv[k]; kconst; zero ssumg ----------------
__global__ __launch_bounds__(256) void k0_prep(const float* __restrict__ anchor,
                                               const float* __restrict__ sigma_p,
                                               const float* __restrict__ wproj,
                                               unsigned short* __restrict__ Wtb,
                                               float* __restrict__ iva2,
                                               float* __restrict__ kconst, float* __restrict__ ssumg) {
    const int c = threadIdx.x;
    const int lane = c & 63, wid = c >> 6;
    __shared__ float red[4][8];
    float kc[8];
#pragma unroll
    for (int k = 0; k < 8; ++k) {
        float sg = sigmoidf_(sigma_p[k * C_ + c]);
        float iv = 1.f / (sg * sg);
        float a = anchor[k * C_ + c];
        iva2[c * 16 + k] = a * iv;
        iva2[c * 16 + 8 + k] = iv;
        kc[k] = a * a * iv;
    }
    for (int s = 0; s < S_; ++s) {
        unsigned r16 = bf16rne_(wproj[s * C_ + c]);
        Wtb[(s * 256 + c) ^ ((s & 7) << 3)] = (unsigned short)r16;
    }
    if (c < 64) ssumg[c] = 0.f;
#pragma unroll
    for (int m = 32; m; m >>= 1) {
#pragma unroll
        for (int k = 0; k < 8; ++k) kc[k] += __shfl_xor(kc[k], m, 64);
    }
    if (lane == 0) {
#pragma unroll
        for (int k = 0; k < 8; ++k) red[wid][k] = kc[k];
    }
    __syncthreads();
    if (c < 8) kconst[c] = red[0][c] + red[1][c] + red[2][c] + red[3][c];
}

// ---------------- K1: MFMA x_proj + fp32 soft + cm + ssum.
// 128 px/block, 4 waves; wave owns 32 px (2 n-tiles) x 64 s (4 m-tiles).
// W bf16 LDS (swizzled); x hi/lo bf16 in per-wave-private LDS (no loop barriers).
// q path uses exact fp32 x from registers; xp via 16x16x32 bf16 MFMA (hi+lo). ----------------
__global__ __launch_bounds__(256) void k1_fused(
    const float* __restrict__ x, const float* __restrict__ contour,
    const unsigned short* __restrict__ Wtb, const float* __restrict__ bproj,
    const float* __restrict__ iva2, const float* __restrict__ kconst,
    float* __restrict__ cm, float* __restrict__ xp, float* __restrict__ soft,
    float* __restrict__ ssumg) {
    __shared__ __align__(16) unsigned short Wl[S_ * C_];     // 32 KB
    __shared__ __align__(16) unsigned short xh[2][128][40];  // 20.5 KB
    __shared__ __align__(16) unsigned short xlo[2][128][40]; // 20.5 KB

    const int tid = threadIdx.x;
    const int lane = tid & 63;
    const int r = __builtin_amdgcn_readfirstlane(tid >> 6);  // wave 0..3
    const int pq = r * 32;              // wave's px offset in block
    const int cpx = lane & 31;          // px within quarter
    const int chh = lane >> 5;          // ch half 0/1
    const int chh16 = chh * 16;
    const int mrow = lane & 15;
    const int g = lane >> 4;            // k-group 0..3
    const int b = blockIdx.y;
    const int px0 = blockIdx.x * 128;
    const int rowq = pq + cpx;
    const int colb = chh16;

    const float* xcol = x + (size_t)b * C_ * HW + px0 + pq + cpx;

#define CVTSTORE(BUFI, VARR)                                                      \
    {                                                                             \
        unsigned hs[16], lz[16];                                                  \
        _Pragma("unroll")                                                         \
        for (int j = 0; j < 16; ++j) {                                            \
            float v = VARR[j];                                                    \
            unsigned h = bf16rne_(v);                                             \
            float hf = __uint_as_float(h << 16);                                  \
            unsigned lo = bf16rne_(v - hf);                                       \
            hs[j] = h; lz[j] = lo;                                                \
        }                                                                         \
        uint4 H0, H1, L0, L1;                                                     \
        H0.x = hs[0] | (hs[1] << 16);  H0.y = hs[2] | (hs[3] << 16);              \
        H0.z = hs[4] | (hs[5] << 16);  H0.w = hs[6] | (hs[7] << 16);              \
        H1.x = hs[8] | (hs[9] << 16);  H1.y = hs[10] | (hs[11] << 16);            \
        H1.z = hs[12] | (hs[13] << 16); H1.w = hs[14] | (hs[15] << 16);           \
        L0.x = lz[0] | (lz[1] << 16);  L0.y = lz[2] | (lz[3] << 16);              \
        L0.z = lz[4] | (lz[5] << 16);  L0.w = lz[6] | (lz[7] << 16);              \
        L1.x = lz[8] | (lz[9] << 16);  L1.y = lz[10] | (lz[11] << 16);            \
        L1.z = lz[12] | (lz[13] << 16); L1.w = lz[14] | (lz[15] << 16);           \
        *(uint4*)&xh[BUFI][rowq][colb] = H0;                                      \
        *(uint4*)&xh[BUFI][rowq][colb + 8] = H1;                                  \
        *(uint4*)&xlo[BUFI][rowq][colb] = L0;                                     \
        *(uint4*)&xlo[BUFI][rowq][colb + 8] = L1;                                 \
    }

    // stage W (linear copy of pre-swizzled global) + chunk 0
    {
        const uint4* src = (const uint4*)Wtb;
        uint4* dst = (uint4*)Wl;
        for (int i = tid; i < S_ * C_ / 8; i += 256) dst[i] = src[i];
    }
    float cxv[16], nxv[16];
#pragma unroll
    for (int j = 0; j < 16; ++j) cxv[j] = xcol[(size_t)(chh16 + j) * HW];
    CVTSTORE(0, cxv)
    __syncthreads();

    f32x4 acc[4][2];
#pragma unroll
    for (int m = 0; m < 4; ++m)
#pragma unroll
        for (int n = 0; n < 2; ++n) acc[m][n] = (f32x4){0.f, 0.f, 0.f, 0.f};
    float q1[8], q2[8];
#pragma unroll
    for (int k = 0; k < 8; ++k) { q1[k] = 0.f; q2[k] = 0.f; }

    auto body = [&](int bufc, int ch0, float (&cur)[16], float (&nxt)[16], bool more) {
        if (more) {
#pragma unroll
            for (int j = 0; j < 16; ++j)
                nxt[j] = xcol[(size_t)(ch0 + 32 + chh16 + j) * HW];
        }
        // MFMA: 4 m-tiles x 2 n-tiles, K=32, hi+lo
#pragma unroll
        for (int m = 0; m < 4; ++m) {
            const int srow = m * 16 + mrow;
            const int widx = (srow * 256 + ch0 + g * 8) ^ ((srow & 7) << 3);
            bf16x8 aw = *(const bf16x8*)&Wl[widx];
#pragma unroll
            for (int n = 0; n < 2; ++n) {
                bf16x8 bh = *(const bf16x8*)&xh[bufc][pq + n * 16 + mrow][g * 8];
                bf16x8 bl = *(const bf16x8*)&xlo[bufc][pq + n * 16 + mrow][g * 8];
                acc[m][n] = __builtin_amdgcn_mfma_f32_16x16x32_bf16(aw, bh, acc[m][n], 0, 0, 0);
                acc[m][n] = __builtin_amdgcn_mfma_f32_16x16x32_bf16(aw, bl, acc[m][n], 0, 0, 0);
            }
        }
        // q path: exact fp32; pair-exchange across half-waves
#pragma unroll
        for (int j = 0; j < 16; ++j) {
            float mine = cur[j];
            float oth = __shfl_xor(mine, 32, 64);
            float xa_ = chh ? oth : mine;   // channel ch0 + j
            float xb_ = chh ? mine : oth;   // channel ch0 + 16 + j
            const float* tA = iva2 + (size_t)(ch0 + j) * 16;
            const float* tB = iva2 + (size_t)(ch0 + 16 + j) * 16;
            float xa2 = xa_ * xa_, xb2 = xb_ * xb_;
#pragma unroll
            for (int k = 0; k < 8; ++k) {
                q1[k] = fmaf(tA[k], xa_, q1[k]);
                q2[k] = fmaf(tA[8 + k], xa2, q2[k]);
                q1[k] = fmaf(tB[k], xb_, q1[k]);
                q2[k] = fmaf(tB[8 + k], xb2, q2[k]);
            }
        }
        if (more) {
            const int nb = bufc ^ 1;
            CVTSTORE(nb, nxt)
        }
    };

#pragma unroll 1
    for (int it = 0; it < 4; ++it) {
        body(0, it * 64, cxv, nxv, true);
        body(1, it * 64 + 32, nxv, cxv, it < 3);
    }
#undef CVTSTORE

    // ---- xp epilogue: D layout col=lane&15, row=(lane>>4)*4+j ----
#pragma unroll
    for (int m = 0; m < 4; ++m)
#pragma unroll
        for (int n = 0; n < 2; ++n)
#pragma unroll
            for (int j = 0; j < 4; ++j) {
                const int s = m * 16 + g * 4 + j;
                const int pxg = px0 + pq + n * 16 + mrow;
                xp[((size_t)b * S_ + s) * HW + pxg] = acc[m][n][j] + bproj[s];
            }

    // ---- softmax (all 8 k in regs, per px) ----
    float lg[8], mx = -1e30f;
#pragma unroll
    for (int k = 0; k < 8; ++k) {
        lg[k] = -0.5f * (q2[k] - 2.f * q1[k] + kconst[k]);
        mx = fmaxf(mx, lg[k]);
    }
    float sm = 0.f;
#pragma unroll
    for (int k = 0; k < 8; ++k) { float e = __expf(lg[k] - mx); lg[k] = e; sm += e; }
    const float inv = 1.f / sm;
    const int mypx = px0 + pq + cpx;
    float ssk[8];
#pragma unroll
    for (int k = 0; k < 8; ++k) {
        float sv = lg[k] * inv;
        if (lane < 32) soft[((size_t)b * K_ + k) * HW + mypx] = sv;
        float t = sv;
        t += __shfl_xor(t, 1, 64);
        t += __shfl_xor(t, 2, 64);
        t += __shfl_xor(t, 4, 64);
        t += __shfl_xor(t, 8, 64);
        t += __shfl_xor(t, 16, 64);
        ssk[k] = t;
    }
    if (lane == 0) {
#pragma unroll
        for (int k = 0; k < 8; ++k) atomicAdd(ssumg + b * 8 + k, ssk[k]);
    }
    if (lane < 32) {
        const float c0v = contour[(size_t)b * 2 * HW + mypx];
        const float c1v = contour[(size_t)b * 2 * HW + HW + mypx];
        cm[(size_t)b * HW + mypx] = sigmoidf_(c1v - c0v);
    }
}

// ---------------- K2: adaptive-pool cropped bins -> x_anchor (B,64,64) ----------------
__global__ void k2_anchor(const float* __restrict__ xp, const float* __restrict__ cm,
                          float* __restrict__ xa) {
    __shared__ float col[128];
    const int i = blockIdx.x;
    const int s = blockIdx.y;
    const int b = blockIdx.z;
    const int w = threadIdx.x;
    const int h0 = ((i + 1) * 128) / 10;
    const int h1 = ((i + 2) * 128 + 9) / 10;
    const float* xps = xp + ((size_t)b * S_ + s) * HW;
    const float* cmb = cm + (size_t)b * HW;
    float v = 0.f;
    for (int h = h0; h < h1; ++h) v += xps[h * 128 + w] * cmb[h * 128 + w];
    col[w] = v;
    __syncthreads();
    if (w < 8) {
        const int j = w;
        const int w0 = ((j + 1) * 128) / 10;
        const int w1 = ((j + 2) * 128 + 9) / 10;
        float sum = 0.f;
        for (int t = w0; t < w1; ++t) sum += col[t];
        xa[((size_t)b * S_ + s) * 64 + i * 8 + j] = sum / (float)((h1 - h0) * (w1 - w0));
    }
}

// ---------------- K3 (s-split): proj = softmax_m( x_anchor^T . x_proj ), in place ----------------
__global__ __launch_bounds__(256, 4) void k3_proj(const float* __restrict__ xa,
                                                  float* __restrict__ xp) {
    const int tid = threadIdx.x;
    const int lane = tid & 63;
    const int wid = __builtin_amdgcn_readfirstlane(tid >> 6);
    const int pg = wid & 1;
    const int sh = wid >> 1;
    const int b = blockIdx.y;
    const int n = blockIdx.x * 128 + pg * 64 + lane;
    const float* xab = xa + (size_t)b * 4096;

    float p[64];
#pragma unroll
    for (int m = 0; m < 64; ++m) p[m] = 0.f;

    float* xpb = xp + (size_t)b * S_ * HW + n;
    const int s0 = sh * 32;
    float xv = xpb[(size_t)s0 * HW];
    for (int si = 0; si < 32; ++si) {
        const int s = s0 + si;
        float xnext = (si < 31) ? xpb[(size_t)(s + 1) * HW] : 0.f;
        const float* row = xab + s * 64;   // uniform -> s_load x16
#pragma unroll
        for (int m = 0; m < 64; ++m) p[m] = fmaf(row[m], xv, p[m]);
        xv = xnext;
    }

    __shared__ float lds[2][64][64];  // 32 KB
    if (sh) {
#pragma unroll
        for (int m = 0; m < 64; ++m) lds[pg][m][lane] = p[m];
    }
    __syncthreads();
    if (!sh) {
#pragma unroll
        for (int m = 0; m < 64; ++m) p[m] += lds[pg][m][lane];
        float mx = -1e30f;
#pragma unroll
        for (int m = 0; m < 64; ++m) mx = fmaxf(mx, p[m]);
        float sm = 0.f;
#pragma unroll
        for (int m = 0; m < 64; ++m) { float e = __expf(p[m] - mx); p[m] = e; sm += e; }
        const float inv = 1.f / sm;
#pragma unroll
        for (int m = 0; m < 64; ++m) xpb[(size_t)m * HW] = p[m] * inv;
    }
}

// ---------------- K5: wsum[b,k,c] = sum_n soft[b,k,n] * x[b,c,n] (float4, 2 c/block) ----------------
__global__ __launch_bounds__(256) void k5_wsum(const float* __restrict__ x,
                                               const float* __restrict__ soft,
                                               float* __restrict__ wsum) {
    const int b = blockIdx.y;
    const int c0 = blockIdx.x * 2;
    const int tid = threadIdx.x;
    float a[16];
#pragma unroll
    for (int i = 0; i < 16; ++i) a[i] = 0.f;
    const float4* sb = (const float4*)(soft + (size_t)b * K_ * HW);
    const float4* xb = (const float4*)(x + ((size_t)b * C_ + c0) * HW);
    for (int i = tid; i < HW / 4; i += 256) {
        float4 sv[8];
#pragma unroll
        for (int k = 0; k < 8; ++k) sv[k] = sb[(size_t)k * (HW / 4) + i];
#pragma unroll
        for (int ci = 0; ci < 2; ++ci) {
            float4 xv = xb[(size_t)ci * (HW / 4) + i];
#pragma unroll
            for (int k = 0; k < 8; ++k) {
                float t = fmaf(sv[k].x, xv.x, fmaf(sv[k].y, xv.y,
                          fmaf(sv[k].z, xv.z, sv[k].w * xv.w)));
                a[ci * 8 + k] += t;
            }
        }
    }
    __shared__ float red[64];
    const int lane = tid & 63, wid = tid >> 6;
#pragma unroll
    for (int o = 0; o < 16; ++o) {
        float v = a[o];
#pragma unroll
        for (int m = 32; m; m >>= 1) v += __shfl_xor(v, m, 64);
        if (lane == 0) red[wid * 16 + o] = v;
    }
    __syncthreads();
    if (tid < 16) {
        float r = red[tid] + red[16 + tid] + red[32 + tid] + red[48 + tid];
        int ci = tid >> 3, k = tid & 7;
        wsum[((size_t)b * K_ + k) * C_ + c0 + ci] = r;
    }
}

// ---------------- K6: nodes, normalize, 3x GCN, relu -> g ----------------
__device__ __forceinline__ float blockSum256(float v, volatile float* sc) {
#pragma unroll
    for (int m = 32; m; m >>= 1) v += __shfl_xor(v, m, 64);
    const int wid = threadIdx.x >> 6, lane = threadIdx.x & 63;
    __syncthreads();
    if (lane == 0) sc[wid] = v;
    __syncthreads();
    return sc[0] + sc[1] + sc[2] + sc[3];
}

__global__ __launch_bounds__(256) void k6_gcn(const float* __restrict__ ssumg,
                                              const float* __restrict__ wsum,
                                              const float* __restrict__ anchor,
                                              const float* __restrict__ sigma_p,
                                              const float* __restrict__ w1,
                                              const float* __restrict__ w2,
                                              const float* __restrict__ w3,
                                              float* __restrict__ gout) {
    const int b = blockIdx.x;
    const int tid = threadIdx.x;
    const int lane = tid & 63, wid = tid >> 6;
    __shared__ float g_lds[2048];
    __shared__ float A[64];
    __shared__ float sc[4];
    __shared__ float red8[4][8];
    __shared__ float ssk_s[8];

    if (tid < 8) ssk_s[tid] = ssumg[b * 8 + tid];
    __syncthreads();
    float ssk[8];
#pragma unroll
    for (int k = 0; k < 8; ++k) ssk[k] = ssk_s[k];

    const int c = tid;
    float node[8];
#pragma unroll
    for (int k = 0; k < 8; ++k) {
        float sg = sigmoidf_(sigma_p[k * C_ + c]);
        float w = wsum[((size_t)b * K_ + k) * C_ + c];
        node[k] = (w - anchor[k * C_ + c] * ssk[k]) / sg / (ssk[k] + 1e-9f);
    }
    float rn[8];
#pragma unroll
    for (int k = 0; k < 8; ++k) rn[k] = node[k] * node[k];
#pragma unroll
    for (int m = 32; m; m >>= 1) {
#pragma unroll
        for (int k = 0; k < 8; ++k) rn[k] += __shfl_xor(rn[k], m, 64);
    }
    if (lane == 0) {
#pragma unroll
        for (int k = 0; k < 8; ++k) red8[wid][k] = rn[k];
    }
    __syncthreads();
#pragma unroll
    for (int k = 0; k < 8; ++k) {
        float t = red8[0][k] + red8[1][k] + red8[2][k] + red8[3][k];
        node[k] /= fmaxf(sqrtf(t), 1e-12f);
    }
    float fs = 0.f;
#pragma unroll
    for (int k = 0; k < 8; ++k) fs += node[k] * node[k];
    float fn = blockSum256(fs, sc);
    float finv = 1.f / fmaxf(sqrtf(fn), 1e-12f);
#pragma unroll
    for (int k = 0; k < 8; ++k) g_lds[tid * 8 + k] = node[k] * finv;
    __syncthreads();

    const float* Ws[3] = {w1, w2, w3};
    for (int L = 0; L < 3; ++L) {
        {
            const int pair = tid >> 2, part = tid & 3;
            const int p = pair >> 3, q = pair & 7;
            float s = 0.f;
            for (int i = part * 64; i < part * 64 + 64; ++i)
                s += g_lds[i * 8 + p] * g_lds[i * 8 + q];
            s += __shfl_xor(s, 1, 64);
            s += __shfl_xor(s, 2, 64);
            if (part == 0) A[pair] = s;
        }
        __syncthreads();
        if (tid < 8) {
            float mx = -1e30f;
            for (int j = 0; j < 8; ++j) mx = fmaxf(mx, A[tid * 8 + j]);
            float sm = 0.f;
            for (int j = 0; j < 8; ++j) { float e = __expf(A[tid * 8 + j] - mx); A[tid * 8 + j] = e; sm += e; }
            float iv = 1.f / sm;
            for (int j = 0; j < 8; ++j) A[tid * 8 + j] *= iv;
        }
        __syncthreads();
        float sup[8];
#pragma unroll
        for (int j = 0; j < 8; ++j) sup[j] = 0.f;
        const float* W = Ws[L];
        float wv[8], wn[8];
#pragma unroll
        for (int i = 0; i < 8; ++i) wv[i] = W[(size_t)i * 256 + tid];
        for (int c0 = 0; c0 < 256; c0 += 8) {
            if (c0 + 8 < 256) {
#pragma unroll
                for (int i = 0; i < 8; ++i) wn[i] = W[(size_t)(c0 + 8 + i) * 256 + tid];
            }
#pragma unroll
            for (int i = 0; i < 8; ++i) {
#pragma unroll
                for (int j = 0; j < 8; ++j)
                    sup[j] = fmaf(g_lds[(c0 + i) * 8 + j], wv[i], sup[j]);
            }
#pragma unroll
            for (int i = 0; i < 8; ++i) wv[i] = wn[i];
        }
        float gn[8];
#pragma unroll
        for (int k = 0; k < 8; ++k) {
            float s = 0.f;
#pragma unroll
            for (int j = 0; j < 8; ++j) s += A[k * 8 + j] * sup[j];
            gn[k] = s;
        }
        __syncthreads();
#pragma unroll
        for (int k = 0; k < 8; ++k) g_lds[tid * 8 + k] = gn[k];
        __syncthreads();
    }
#pragma unroll
    for (int k = 0; k < 8; ++k)
        gout[(size_t)b * 2048 + tid * 8 + k] = fmaxf(g_lds[tid * 8 + k], 0.f);
}

extern "C" void kernel_launch(void* const* d_in, const int* in_sizes, int n_in,
                              void* d_out, int out_size, void* d_ws, size_t ws_size,
                              hipStream_t stream) {
    const float* x = (const float*)d_in[0];
    const float* contour = (const float*)d_in[1];
    const float* wproj = (const float*)d_in[4];
    const float* bproj = (const float*)d_in[5];
    const float* anchor = (const float*)d_in[6];
    const float* sigma_p = (const float*)d_in[7];
    const float* w1 = (const float*)d_in[8];
    const float* w2 = (const float*)d_in[9];
    const float* w3 = (const float*)d_in[10];

    float* out = (float*)d_out;
    float* g_out = out;                        // (B,256,8)
    float* xp = out + 16384;                   // proj region (B,64,HW)
    float* soft = out + 16384 + 8388608;       // (B,8,HW)

    float* ws = (float*)d_ws;
    float* cm = ws;                             // 131072
    float* xa = ws + 131072;                    // 32768
    float* wsum = ws + 163840;                  // 16384
    float* kconst = ws + 180224;                // 8
    float* ssumg = ws + 180232;                 // 64
    float* iva2 = ws + 180296;                  // 4096
    unsigned short* Wtb = (unsigned short*)(ws + 184392);  // 16384 ushorts (32KB)

    k0_prep<<<1, 256, 0, stream>>>(anchor, sigma_p, wproj, Wtb, iva2, kconst, ssumg);
    k1_fused<<<dim3(HW / 128, B_), 256, 0, stream>>>(x, contour, Wtb, bproj, iva2, kconst,
                                                     cm, xp, soft, ssumg);
    k2_anchor<<<dim3(8, 64, B_), 128, 0, stream>>>(xp, cm, xa);
    k3_proj<<<dim3(HW / 128, B_), 256, 0, stream>>>(xa, xp);
    k5_wsum<<<dim3(128, B_), 256, 0, stream>>>(x, soft, wsum);
    k6_gcn<<<B_, 256, 0, stream>>>(ssumg, wsum, anchor, sigma_p, w1, w2, w3, g_out);
}

// Round 13
// 232.817 us; speedup vs baseline: 1.9677x; 1.9677x over previous
//
#include <hip/hip_runtime.h>
#include <math.h>

#define HW 16384
#define B_ 8
#define C_ 256
#define S_ 64
#define K_ 8

__device__ __forceinline__ float sigmoidf_(float z) { return 1.f / (1.f + __expf(-z)); }

// ---------------- K0: precompute Wtb[c][s] = bf16(wproj^T), iva2[c][r][4], kconst; zero ssumg ----------------
__global__ __launch_bounds__(256) void k0_prep(const float* __restrict__ anchor,
                                               const float* __restrict__ sigma_p,
                                               const float* __restrict__ wproj,
                                               unsigned short* __restrict__ Wtb,
                                               float* __restrict__ iva2,
                                               float* __restrict__ kconst, float* __restrict__ ssumg) {
    const int c = threadIdx.x;
    const int lane = c & 63, wid = c >> 6;
    __shared__ float red[4][8];
    float kc[8];
#pragma unroll
    for (int k = 0; k < 8; ++k) {
        float sg = sigmoidf_(sigma_p[k * C_ + c]);
        float iv = 1.f / (sg * sg);
        float a = anchor[k * C_ + c];
        const int r = k >> 1, j = k & 1;
        iva2[c * 16 + r * 4 + j] = a * iv;       // aiv for k=2r+j
        iva2[c * 16 + r * 4 + 2 + j] = iv;       // iv  for k=2r+j
        kc[k] = a * a * iv;
    }
    for (int s = 0; s < S_; ++s) {
        unsigned u = __float_as_uint(wproj[s * C_ + c]);
        unsigned r16 = (u + 0x7fffu + ((u >> 16) & 1u)) >> 16;   // RNE bf16
        Wtb[c * S_ + s] = (unsigned short)r16;
    }
    if (c < 64) ssumg[c] = 0.f;
#pragma unroll
    for (int m = 32; m; m >>= 1) {
#pragma unroll
        for (int k = 0; k < 8; ++k) kc[k] += __shfl_xor(kc[k], m, 64);
    }
    if (lane == 0) {
#pragma unroll
        for (int k = 0; k < 8; ++k) red[wid][k] = kc[k];
    }
    __syncthreads();
    if (c < 8) kconst[c] = red[0][c] + red[1][c] + red[2][c] + red[3][c];
}

// ---------------- K1: fused x_proj + soft + cm + ssum.  (round-10 structure + Ql in LDS)
// 4 waves / 256 px per block; 4 px per thread (float4).
// Wave r: s-rows [16r,16r+16) + k-pair {2r,2r+1}.
// W in LDS as bf16 (32KB): 2 uniform b128 per channel per wave.
// q-tables in LDS (16KB): 1 uniform b128 per channel per wave (NO SMEM in loop).
// x staged in LDS, 8-channel chunks double-buffered (16KB), register prefetch. ----------------
__global__ __launch_bounds__(256) void k1_fused(
    const float* __restrict__ x, const float* __restrict__ contour,
    const unsigned short* __restrict__ Wtb, const float* __restrict__ bproj,
    const float* __restrict__ iva2, const float* __restrict__ kconst,
    float* __restrict__ cm, float* __restrict__ xp, float* __restrict__ soft,
    float* __restrict__ ssumg) {
    __shared__ unsigned short Wl[C_ * S_];   // 32 KB bf16 [c][s]
    __shared__ float xl[2][8][256];          // 16 KB [buf][ch][px]
    __shared__ float Ql[C_ * 16];            // 16 KB [c][16]
    const int tid = threadIdx.x;
    const int lane = tid & 63;
    const int r = __builtin_amdgcn_readfirstlane(tid >> 6);  // wave role 0..3
    const int s0 = r * 16;
    const int b = blockIdx.y;
    const int pl = lane * 4;
    const int px = blockIdx.x * 256 + pl;

    const float* xb = x + (size_t)b * C_ * HW + px;

    // stage W + q-tables (once) + x chunk 0 (wave r loads channels r and 4+r)
    {
        const uint4* src = (const uint4*)Wtb;
        uint4* dst = (uint4*)Wl;
        for (int i = tid; i < C_ * S_ / 8; i += 256) dst[i] = src[i];
        const float4* qs = (const float4*)iva2;
        float4* qd = (float4*)Ql;
        for (int i = tid; i < C_ * 16 / 4; i += 256) qd[i] = qs[i];
        *(float4*)&xl[0][r][pl] = *(const float4*)(xb + (size_t)r * HW);
        *(float4*)&xl[0][4 + r][pl] = *(const float4*)(xb + (size_t)(4 + r) * HW);
    }
    __syncthreads();

    float4 acc[16];
#pragma unroll
    for (int s = 0; s < 16; ++s) acc[s] = make_float4(0.f, 0.f, 0.f, 0.f);
    float4 q1a = make_float4(0.f, 0.f, 0.f, 0.f), q1b = q1a, q2a = q1a, q2b = q1a;

    int buf = 0;
    for (int ch = 0; ch < C_; ch += 8) {
        const bool more = (ch + 8) < C_;
        float4 nv0, nv1;
        if (more) {
            nv0 = *(const float4*)(xb + (size_t)(ch + 8 + r) * HW);
            nv1 = *(const float4*)(xb + (size_t)(ch + 12 + r) * HW);
        }
#pragma unroll
        for (int j = 0; j < 8; ++j) {
            const int c = ch + j;
            const float4 xv = *(const float4*)&xl[buf][j][pl];
            const unsigned short* wr = Wl + (size_t)c * S_ + s0;
            const uint4 wA = *(const uint4*)wr;          // s0..s0+8 (bf16 pairs)
            const uint4 wB = *(const uint4*)(wr + 8);    // s0+8..s0+16
            const unsigned pw[8] = {wA.x, wA.y, wA.z, wA.w, wB.x, wB.y, wB.z, wB.w};
#pragma unroll
            for (int p = 0; p < 8; ++p) {
                const float wlo = __uint_as_float(pw[p] << 16);
                const float whi = __uint_as_float(pw[p] & 0xffff0000u);
                float4& aL = acc[2 * p];
                float4& aH = acc[2 * p + 1];
                aL.x = fmaf(wlo, xv.x, aL.x); aL.y = fmaf(wlo, xv.y, aL.y);
                aL.z = fmaf(wlo, xv.z, aL.z); aL.w = fmaf(wlo, xv.w, aL.w);
                aH.x = fmaf(whi, xv.x, aH.x); aH.y = fmaf(whi, xv.y, aH.y);
                aH.z = fmaf(whi, xv.z, aH.z); aH.w = fmaf(whi, xv.w, aH.w);
            }
            const float4 t = *(const float4*)&Ql[c * 16 + r * 4];   // uniform -> ds_read_b128
            float4 x2;
            x2.x = xv.x * xv.x; x2.y = xv.y * xv.y; x2.z = xv.z * xv.z; x2.w = xv.w * xv.w;
            q1a.x = fmaf(t.x, xv.x, q1a.x); q1a.y = fmaf(t.x, xv.y, q1a.y);
            q1a.z = fmaf(t.x, xv.z, q1a.z); q1a.w = fmaf(t.x, xv.w, q1a.w);
            q1b.x = fmaf(t.y, xv.x, q1b.x); q1b.y = fmaf(t.y, xv.y, q1b.y);
            q1b.z = fmaf(t.y, xv.z, q1b.z); q1b.w = fmaf(t.y, xv.w, q1b.w);
            q2a.x = fmaf(t.z, x2.x, q2a.x); q2a.y = fmaf(t.z, x2.y, q2a.y);
            q2a.z = fmaf(t.z, x2.z, q2a.z); q2a.w = fmaf(t.z, x2.w, q2a.w);
            q2b.x = fmaf(t.w, x2.x, q2b.x); q2b.y = fmaf(t.w, x2.y, q2b.y);
            q2b.z = fmaf(t.w, x2.z, q2b.z); q2b.w = fmaf(t.w, x2.w, q2b.w);
        }
        if (more) {
            *(float4*)&xl[buf ^ 1][r][pl] = nv0;
            *(float4*)&xl[buf ^ 1][4 + r][pl] = nv1;
        }
        __syncthreads();
        buf ^= 1;
    }

    // xp writes: this wave's 16 s-rows, float4 per row
#pragma unroll
    for (int s = 0; s < 16; ++s) {
        const float bias = bproj[s0 + s];
        float4 o;
        o.x = acc[s].x + bias; o.y = acc[s].y + bias;
        o.z = acc[s].z + bias; o.w = acc[s].w + bias;
        *(float4*)(xp + ((size_t)b * S_ + s0 + s) * HW + px) = o;
    }

    // q combine via LDS (reuse xl: q1 at [k*256+px], q2 at [2048 + k*256+px])
    float* qb = (float*)xl;
    *(float4*)&qb[(2 * r) * 256 + pl] = q1a;
    *(float4*)&qb[(2 * r + 1) * 256 + pl] = q1b;
    *(float4*)&qb[2048 + (2 * r) * 256 + pl] = q2a;
    *(float4*)&qb[2048 + (2 * r + 1) * 256 + pl] = q2b;
    __syncthreads();

    if (r == 0) {
        // softmax over k for 4 px per lane
        float4 lgv[K_];
        float4 mx = make_float4(-1e30f, -1e30f, -1e30f, -1e30f);
#pragma unroll
        for (int k = 0; k < K_; ++k) {
            const float4 q1k = *(const float4*)&qb[k * 256 + pl];
            const float4 q2k = *(const float4*)&qb[2048 + k * 256 + pl];
            const float kc = kconst[k];
            lgv[k].x = -0.5f * (q2k.x - 2.f * q1k.x + kc);
            lgv[k].y = -0.5f * (q2k.y - 2.f * q1k.y + kc);
            lgv[k].z = -0.5f * (q2k.z - 2.f * q1k.z + kc);
            lgv[k].w = -0.5f * (q2k.w - 2.f * q1k.w + kc);
            mx.x = fmaxf(mx.x, lgv[k].x); mx.y = fmaxf(mx.y, lgv[k].y);
            mx.z = fmaxf(mx.z, lgv[k].z); mx.w = fmaxf(mx.w, lgv[k].w);
        }
        float4 sm = make_float4(0.f, 0.f, 0.f, 0.f);
#pragma unroll
        for (int k = 0; k < K_; ++k) {
            lgv[k].x = __expf(lgv[k].x - mx.x); sm.x += lgv[k].x;
            lgv[k].y = __expf(lgv[k].y - mx.y); sm.y += lgv[k].y;
            lgv[k].z = __expf(lgv[k].z - mx.z); sm.z += lgv[k].z;
            lgv[k].w = __expf(lgv[k].w - mx.w); sm.w += lgv[k].w;
        }
        const float ix = 1.f / sm.x, iy = 1.f / sm.y, iz = 1.f / sm.z, iw = 1.f / sm.w;
        float ssk[K_];
#pragma unroll
        for (int k = 0; k < K_; ++k) {
            float4 o;
            o.x = lgv[k].x * ix; o.y = lgv[k].y * iy;
            o.z = lgv[k].z * iz; o.w = lgv[k].w * iw;
            *(float4*)(soft + ((size_t)b * K_ + k) * HW + px) = o;
            ssk[k] = (o.x + o.y) + (o.z + o.w);
        }
#pragma unroll
        for (int m = 32; m; m >>= 1) {
#pragma unroll
            for (int k = 0; k < K_; ++k) ssk[k] += __shfl_xor(ssk[k], m, 64);
        }
        if (lane == 0) {
#pragma unroll
            for (int k = 0; k < K_; ++k) atomicAdd(ssumg + b * 8 + k, ssk[k]);
        }

        // cm = sigmoid(c1 - c0)
        const float4 c0 = *(const float4*)(contour + (size_t)b * 2 * HW + px);
        const float4 c1 = *(const float4*)(contour + (size_t)b * 2 * HW + HW + px);
        float4 cv;
        cv.x = sigmoidf_(c1.x - c0.x); cv.y = sigmoidf_(c1.y - c0.y);
        cv.z = sigmoidf_(c1.z - c0.z); cv.w = sigmoidf_(c1.w - c0.w);
        *(float4*)(cm + (size_t)b * HW + px) = cv;
    }
}

// ---------------- K2: adaptive-pool cropped bins -> x_anchor (B,64,64) ----------------
__global__ void k2_anchor(const float* __restrict__ xp, const float* __restrict__ cm,
                          float* __restrict__ xa) {
    __shared__ float col[128];
    const int i = blockIdx.x;
    const int s = blockIdx.y;
    const int b = blockIdx.z;
    const int w = threadIdx.x;
    const int h0 = ((i + 1) * 128) / 10;
    const int h1 = ((i + 2) * 128 + 9) / 10;
    const float* xps = xp + ((size_t)b * S_ + s) * HW;
    const float* cmb = cm + (size_t)b * HW;
    float v = 0.f;
    for (int h = h0; h < h1; ++h) v += xps[h * 128 + w] * cmb[h * 128 + w];
    col[w] = v;
    __syncthreads();
    if (w < 8) {
        const int j = w;
        const int w0 = ((j + 1) * 128) / 10;
        const int w1 = ((j + 2) * 128 + 9) / 10;
        float sum = 0.f;
        for (int t = w0; t < w1; ++t) sum += col[t];
        xa[((size_t)b * S_ + s) * 64 + i * 8 + j] = sum / (float)((h1 - h0) * (w1 - w0));
    }
}

// ---------------- K3 (s-split): proj = softmax_m( x_anchor^T . x_proj ), in place ----------------
__global__ __launch_bounds__(256, 4) void k3_proj(const float* __restrict__ xa,
                                                  float* __restrict__ xp) {
    const int tid = threadIdx.x;
    const int lane = tid & 63;
    const int wid = __builtin_amdgcn_readfirstlane(tid >> 6);
    const int pg = wid & 1;
    const int sh = wid >> 1;
    const int b = blockIdx.y;
    const int n = blockIdx.x * 128 + pg * 64 + lane;
    const float* xab = xa + (size_t)b * 4096;

    float p[64];
#pragma unroll
    for (int m = 0; m < 64; ++m) p[m] = 0.f;

    float* xpb = xp + (size_t)b * S_ * HW + n;
    const int s0 = sh * 32;
    float xv = xpb[(size_t)s0 * HW];
    for (int si = 0; si < 32; ++si) {
        const int s = s0 + si;
        float xnext = (si < 31) ? xpb[(size_t)(s + 1) * HW] : 0.f;
        const float* row = xab + s * 64;   // uniform -> s_load x16
#pragma unroll
        for (int m = 0; m < 64; ++m) p[m] = fmaf(row[m], xv, p[m]);
        xv = xnext;
    }

    __shared__ float lds[2][64][64];  // 32 KB
    if (sh) {
#pragma unroll
        for (int m = 0; m < 64; ++m) lds[pg][m][lane] = p[m];
    }
    __syncthreads();
    if (!sh) {
#pragma unroll
        for (int m = 0; m < 64; ++m) p[m] += lds[pg][m][lane];
        float mx = -1e30f;
#pragma unroll
        for (int m = 0; m < 64; ++m) mx = fmaxf(mx, p[m]);
        float sm = 0.f;
#pragma unroll
        for (int m = 0; m < 64; ++m) { float e = __expf(p[m] - mx); p[m] = e; sm += e; }
        const float inv = 1.f / sm;
#pragma unroll
        for (int m = 0; m < 64; ++m) xpb[(size_t)m * HW] = p[m] * inv;
    }
}

// ---------------- K5: wsum[b,k,c] = sum_n soft[b,k,n] * x[b,c,n] (float4, 2 c/block) ----------------
__global__ __launch_bounds__(256) void k5_wsum(const float* __restrict__ x,
                                               const float* __restrict__ soft,
                                               float* __restrict__ wsum) {
    const int b = blockIdx.y;
    const int c0 = blockIdx.x * 2;
    const int tid = threadIdx.x;
    float a[16];
#pragma unroll
    for (int i = 0; i < 16; ++i) a[i] = 0.f;
    const float4* sb = (const float4*)(soft + (size_t)b * K_ * HW);
    const float4* xb = (const float4*)(x + ((size_t)b * C_ + c0) * HW);
    for (int i = tid; i < HW / 4; i += 256) {
        float4 sv[8];
#pragma unroll
        for (int k = 0; k < 8; ++k) sv[k] = sb[(size_t)k * (HW / 4) + i];
#pragma unroll
        for (int ci = 0; ci < 2; ++ci) {
            float4 xv = xb[(size_t)ci * (HW / 4) + i];
#pragma unroll
            for (int k = 0; k < 8; ++k) {
                float t = fmaf(sv[k].x, xv.x, fmaf(sv[k].y, xv.y,
                          fmaf(sv[k].z, xv.z, sv[k].w * xv.w)));
                a[ci * 8 + k] += t;
            }
        }
    }
    __shared__ float red[64];
    const int lane = tid & 63, wid = tid >> 6;
#pragma unroll
    for (int o = 0; o < 16; ++o) {
        float v = a[o];
#pragma unroll
        for (int m = 32; m; m >>= 1) v += __shfl_xor(v, m, 64);
        if (lane == 0) red[wid * 16 + o] = v;
    }
    __syncthreads();
    if (tid < 16) {
        float r = red[tid] + red[16 + tid] + red[32 + tid] + red[48 + tid];
        int ci = tid >> 3, k = tid & 7;
        wsum[((size_t)b * K_ + k) * C_ + c0 + ci] = r;
    }
}

// ---------------- K6: nodes, normalize, 3x GCN, relu -> g ----------------
__device__ __forceinline__ float blockSum256(float v, volatile float* sc) {
#pragma unroll
    for (int m = 32; m; m >>= 1) v += __shfl_xor(v, m, 64);
    const int wid = threadIdx.x >> 6, lane = threadIdx.x & 63;
    __syncthreads();
    if (lane == 0) sc[wid] = v;
    __syncthreads();
    return sc[0] + sc[1] + sc[2] + sc[3];
}

__global__ __launch_bounds__(256) void k6_gcn(const float* __restrict__ ssumg,
                                              const float* __restrict__ wsum,
                                              const float* __restrict__ anchor,
                                              const float* __restrict__ sigma_p,
                                              const float* __restrict__ w1,
                                              const float* __restrict__ w2,
                                              const float* __restrict__ w3,
                                              float* __restrict__ gout) {
    const int b = blockIdx.x;
    const int tid = threadIdx.x;
    const int lane = tid & 63, wid = tid >> 6;
    __shared__ float g_lds[2048];
    __shared__ float A[64];
    __shared__ float sc[4];
    __shared__ float red8[4][8];
    __shared__ float ssk_s[8];

    if (tid < 8) ssk_s[tid] = ssumg[b * 8 + tid];
    __syncthreads();
    float ssk[8];
#pragma unroll
    for (int k = 0; k < 8; ++k) ssk[k] = ssk_s[k];

    const int c = tid;
    float node[8];
#pragma unroll
    for (int k = 0; k < 8; ++k) {
        float sg = sigmoidf_(sigma_p[k * C_ + c]);
        float w = wsum[((size_t)b * K_ + k) * C_ + c];
        node[k] = (w - anchor[k * C_ + c] * ssk[k]) / sg / (ssk[k] + 1e-9f);
    }
    float rn[8];
#pragma unroll
    for (int k = 0; k < 8; ++k) rn[k] = node[k] * node[k];
#pragma unroll
    for (int m = 32; m; m >>= 1) {
#pragma unroll
        for (int k = 0; k < 8; ++k) rn[k] += __shfl_xor(rn[k], m, 64);
    }
    if (lane == 0) {
#pragma unroll
        for (int k = 0; k < 8; ++k) red8[wid][k] = rn[k];
    }
    __syncthreads();
#pragma unroll
    for (int k = 0; k < 8; ++k) {
        float t = red8[0][k] + red8[1][k] + red8[2][k] + red8[3][k];
        node[k] /= fmaxf(sqrtf(t), 1e-12f);
    }
    float fs = 0.f;
#pragma unroll
    for (int k = 0; k < 8; ++k) fs += node[k] * node[k];
    float fn = blockSum256(fs, sc);
    float finv = 1.f / fmaxf(sqrtf(fn), 1e-12f);
#pragma unroll
    for (int k = 0; k < 8; ++k) g_lds[tid * 8 + k] = node[k] * finv;
    __syncthreads();

    const float* Ws[3] = {w1, w2, w3};
    for (int L = 0; L < 3; ++L) {
        {
            const int pair = tid >> 2, part = tid & 3;
            const int p = pair >> 3, q = pair & 7;
            float s = 0.f;
            for (int i = part * 64; i < part * 64 + 64; ++i)
                s += g_lds[i * 8 + p] * g_lds[i * 8 + q];
            s += __shfl_xor(s, 1, 64);
            s += __shfl_xor(s, 2, 64);
            if (part == 0) A[pair] = s;
        }
        __syncthreads();
        if (tid < 8) {
            float mx = -1e30f;
            for (int j = 0; j < 8; ++j) mx = fmaxf(mx, A[tid * 8 + j]);
            float sm = 0.f;
            for (int j = 0; j < 8; ++j) { float e = __expf(A[tid * 8 + j] - mx); A[tid * 8 + j] = e; sm += e; }
            float iv = 1.f / sm;
            for (int j = 0; j < 8; ++j) A[tid * 8 + j] *= iv;
        }
        __syncthreads();
        float sup[8];
#pragma unroll
        for (int j = 0; j < 8; ++j) sup[j] = 0.f;
        const float* W = Ws[L];
        float wv[8], wn[8];
#pragma unroll
        for (int i = 0; i < 8; ++i) wv[i] = W[(size_t)i * 256 + tid];
        for (int c0 = 0; c0 < 256; c0 += 8) {
            if (c0 + 8 < 256) {
#pragma unroll
                for (int i = 0; i < 8; ++i) wn[i] = W[(size_t)(c0 + 8 + i) * 256 + tid];
            }
#pragma unroll
            for (int i = 0; i < 8; ++i) {
#pragma unroll
                for (int j = 0; j < 8; ++j)
                    sup[j] = fmaf(g_lds[(c0 + i) * 8 + j], wv[i], sup[j]);
            }
#pragma unroll
            for (int i = 0; i < 8; ++i) wv[i] = wn[i];
        }
        float gn[8];
#pragma unroll
        for (int k = 0; k < 8; ++k) {
            float s = 0.f;
#pragma unroll
            for (int j = 0; j < 8; ++j) s += A[k * 8 + j] * sup[j];
            gn[k] = s;
        }
        __syncthreads();
#pragma unroll
        for (int k = 0; k < 8; ++k) g_lds[tid * 8 + k] = gn[k];
        __syncthreads();
    }
#pragma unroll
    for (int k = 0; k < 8; ++k)
        gout[(size_t)b * 2048 + tid * 8 + k] = fmaxf(g_lds[tid * 8 + k], 0.f);
}

extern "C" void kernel_launch(void* const* d_in, const int* in_sizes, int n_in,
                              void* d_out, int out_size, void* d_ws, size_t ws_size,
                              hipStream_t stream) {
    const float* x = (const float*)d_in[0];
    const float* contour = (const float*)d_in[1];
    const float* wproj = (const float*)d_in[4];
    const float* bproj = (const float*)d_in[5];
    const float* anchor = (const float*)d_in[6];
    const float* sigma_p = (const float*)d_in[7];
    const float* w1 = (const float*)d_in[8];
    const float* w2 = (const float*)d_in[9];
    const float* w3 = (const float*)d_in[10];

    float* out = (float*)d_out;
    float* g_out = out;                        // (B,256,8)
    float* xp = out + 16384;                   // proj region (B,64,HW)
    float* soft = out + 16384 + 8388608;       // (B,8,HW)

    float* ws = (float*)d_ws;
    float* cm = ws;                             // 131072
    float* xa = ws + 131072;                    // 32768
    float* wsum = ws + 163840;                  // 16384
    float* kconst = ws + 180224;                // 8
    float* ssumg = ws + 180232;                 // 64
    float* iva2 = ws + 180296;                  // 4096
    unsigned short* Wtb = (unsigned short*)(ws + 184392);  // 16384 ushorts (32KB)

    k0_prep<<<1, 256, 0, stream>>>(anchor, sigma_p, wproj, Wtb, iva2, kconst, ssumg);
    k1_fused<<<dim3(HW / 256, B_), 256, 0, stream>>>(x, contour, Wtb, bproj, iva2, kconst,
                                                     cm, xp, soft, ssumg);
    k2_anchor<<<dim3(8, 64, B_), 128, 0, stream>>>(xp, cm, xa);
    k3_proj<<<dim3(HW / 128, B_), 256, 0, stream>>>(xa, xp);
    k5_wsum<<<dim3(128, B_), 256, 0, stream>>>(x, soft, wsum);
    k6_gcn<<<B_, 256, 0, stream>>>(ssumg, wsum, anchor, sigma_p, w1, w2, w3, g_out);
}